// Round 7
// baseline (1836.922 us; speedup 1.0000x reference)
//
#include <hip/hip_runtime.h>
#include <math.h>

#define BN_EPS 1e-5f
constexpr int Bc = 8, Nc = 8192, Sc = 1024, CINc = 64;

typedef float v2f __attribute__((ext_vector_type(2)));

// ---------------- DPP reduction helpers ----------------
template <int CTRL, int RMASK>
__device__ __forceinline__ unsigned long long dpp_maxu64(unsigned long long k) {
  int lo = (int)(unsigned)k, hi = (int)(unsigned)(k >> 32);
  int olo = __builtin_amdgcn_update_dpp(lo, lo, CTRL, RMASK, 0xF, false);
  int ohi = __builtin_amdgcn_update_dpp(hi, hi, CTRL, RMASK, 0xF, false);
  unsigned long long ok = ((unsigned long long)(unsigned)ohi << 32) | (unsigned)olo;
  return ok > k ? ok : k;
}
template <int CTRL, int RMASK>
__device__ __forceinline__ v2f dpp_sumstep2(v2f v) {
  int olo = __builtin_amdgcn_update_dpp(0, __float_as_int(v.x), CTRL, RMASK, 0xF, false);
  int ohi = __builtin_amdgcn_update_dpp(0, __float_as_int(v.y), CTRL, RMASK, 0xF, false);
  v2f o = {__int_as_float(olo), __int_as_float(ohi)};
  return v + o;
}
__device__ __forceinline__ v2f dpp_rowsum2(v2f v) {
  v = dpp_sumstep2<0x111, 0xF>(v);
  v = dpp_sumstep2<0x112, 0xF>(v);
  v = dpp_sumstep2<0x114, 0xF>(v);
  v = dpp_sumstep2<0x118, 0xF>(v);
  return v;  // lane15 of each 16-lane row holds row total
}
template <int CTRL, int RMASK>
__device__ __forceinline__ float dpp_maxstep(float v) {
  float o = __int_as_float(
      __builtin_amdgcn_update_dpp(__float_as_int(v), __float_as_int(v), CTRL, RMASK, 0xF, false));
  return fmaxf(v, o);
}
template <int CTRL, int RMASK>
__device__ __forceinline__ float dpp_minstep(float v) {
  float o = __int_as_float(
      __builtin_amdgcn_update_dpp(__float_as_int(v), __float_as_int(v), CTRL, RMASK, 0xF, false));
  return fminf(v, o);
}
template <int K>
__device__ __forceinline__ float dpp_maxK(float v) {
  v = dpp_maxstep<0x111, 0xF>(v);
  v = dpp_maxstep<0x112, 0xF>(v);
  v = dpp_maxstep<0x114, 0xF>(v);
  v = dpp_maxstep<0x118, 0xF>(v);
  if (K == 32) v = dpp_maxstep<0x142, 0xA>(v);
  return v;
}
template <int K>
__device__ __forceinline__ float dpp_minK(float v) {
  v = dpp_minstep<0x111, 0xF>(v);
  v = dpp_minstep<0x112, 0xF>(v);
  v = dpp_minstep<0x114, 0xF>(v);
  v = dpp_minstep<0x118, 0xF>(v);
  if (K == 32) v = dpp_minstep<0x142, 0xA>(v);
  return v;
}

// ---------------- shared pproj body (P[n][64] = W_pts . points + bias) ----------------
__device__ __forceinline__ void pproj_body(int i, const float* __restrict__ pts,
                                           const float* __restrict__ wl,
                                           const float* __restrict__ bl,
                                           float* __restrict__ P) {
  int b = i >> 13, n = i & 8191;
  const float* pb = pts + (size_t)b * CINc * Nc + n;
  v2f acc[32];
  const v2f* bl2 = (const v2f*)bl;
#pragma unroll
  for (int o2 = 0; o2 < 32; o2++) acc[o2] = bl2[o2];
  for (int c = 0; c < CINc; c++) {
    float xv = pb[(size_t)c * Nc];
    v2f xv2 = {xv, xv};
    const v2f* wr = (const v2f*)(wl + c * 64);
#pragma unroll
    for (int o2 = 0; o2 < 32; o2++) acc[o2] = __builtin_elementwise_fma(wr[o2], xv2, acc[o2]);
  }
  float4* Pn = (float4*)(P + (size_t)i * 64);
#pragma unroll
  for (int o4 = 0; o4 < 16; o4++)
    Pn[o4] = make_float4(acc[2 * o4].x, acc[2 * o4].y, acc[2 * o4 + 1].x, acc[2 * o4 + 1].y);
}

// ---------------- mega kernel: blocks 0-7 fps, 8-263 xyzt, 264-519 pproj(br0) ----------------
__global__ __launch_bounds__(256) void mega_kernel(const float* __restrict__ xyz,
                                                   const float* __restrict__ pts,
                                                   const float* __restrict__ w00,
                                                   const float* __restrict__ b00,
                                                   float4* __restrict__ xyzT,
                                                   float4* __restrict__ nx,
                                                   float* __restrict__ out0,
                                                   float* __restrict__ P) {
  __shared__ alignas(16) char smemc[102528];
  int bid = blockIdx.x, t = threadIdx.x;
  if (bid < 8) {
    float* xs = (float*)smemc;
    float* ys = xs + Nc;
    float* zs = ys + Nc;
    int* idxs = (int*)(smemc + 98304);
    unsigned long long* red = (unsigned long long*)(smemc + 102400);  // [2][4]
    const float* xb = xyz + (size_t)bid * 3 * Nc;
    v2f px[16], py[16], pz[16], dd[16];
#pragma unroll
    for (int j = 0; j < 16; j++) {
      int n0 = (2 * j) * 256 + t, n1 = (2 * j + 1) * 256 + t;
      float x0 = xb[n0], y0 = xb[Nc + n0], z0 = xb[2 * Nc + n0];
      float x1 = xb[n1], y1 = xb[Nc + n1], z1 = xb[2 * Nc + n1];
      xs[n0] = x0; ys[n0] = y0; zs[n0] = z0;
      xs[n1] = x1; ys[n1] = y1; zs[n1] = z1;
      px[j] = (v2f){x0, x1}; py[j] = (v2f){y0, y1}; pz[j] = (v2f){z0, z1};
      dd[j] = (v2f){1e10f, 1e10f};
    }
    int w = t >> 6;
    __syncthreads();
    int curIdx = 0;
    for (int i = 0; i < Sc; i++) {
      float cx = xs[curIdx], cy = ys[curIdx], cz = zs[curIdx];  // LDS broadcast
      if (t == 0) idxs[i] = curIdx;
      v2f cx2 = (v2f){cx, cx}, cy2 = (v2f){cy, cy}, cz2 = (v2f){cz, cz};
      v2f bdv0 = (v2f){-1.f, -1.f}, bdv1 = (v2f){-1.f, -1.f};
#pragma unroll
      for (int j = 0; j < 16; j++) {
        v2f dx = px[j] - cx2, dy = py[j] - cy2, dz = pz[j] - cz2;
        v2f d = __builtin_elementwise_fma(dz, dz, __builtin_elementwise_fma(dy, dy, dx * dx));
        d = __builtin_elementwise_min(dd[j], d);
        dd[j] = d;
        if (j & 1) bdv1 = __builtin_elementwise_max(bdv1, d);
        else bdv0 = __builtin_elementwise_max(bdv0, d);
      }
      v2f bdv = __builtin_elementwise_max(bdv0, bdv1);
      float bd = fmaxf(bdv.x, bdv.y);
      unsigned best0 = 0u, best1 = 0u;
#pragma unroll
      for (int j = 0; j < 16; j++) {
        unsigned n0 = (unsigned)((2 * j) * 256 + t);
        unsigned c0 = (dd[j].x == bd) ? ~n0 : 0u;
        unsigned c1 = (dd[j].y == bd) ? ~(n0 + 256u) : 0u;
        unsigned cc = c0 > c1 ? c0 : c1;
        if (j & 1) best1 = cc > best1 ? cc : best1;
        else best0 = cc > best0 ? cc : best0;
      }
      unsigned best = best0 > best1 ? best0 : best1;
      unsigned long long key = ((unsigned long long)__float_as_uint(bd) << 32) | best;
      key = dpp_maxu64<0x111, 0xF>(key);
      key = dpp_maxu64<0x112, 0xF>(key);
      key = dpp_maxu64<0x114, 0xF>(key);
      key = dpp_maxu64<0x118, 0xF>(key);
      key = dpp_maxu64<0x142, 0xA>(key);
      key = dpp_maxu64<0x143, 0xC>(key);
      if ((t & 63) == 63) red[(i & 1) * 4 + w] = key;
      __syncthreads();
      const unsigned long long* rr = red + (i & 1) * 4;
      unsigned long long k2 = rr[0];
      unsigned long long o1 = rr[1], o2v = rr[2], o3 = rr[3];
      k2 = (o1 > k2) ? o1 : k2;
      k2 = (o2v > k2) ? o2v : k2;
      k2 = (o3 > k2) ? o3 : k2;
      curIdx = (int)(~(unsigned)(k2 & 0xFFFFFFFFull));
    }
    __syncthreads();
    for (int i2 = t; i2 < Sc; i2 += 256) {
      int idx = idxs[i2];
      float x = xs[idx], y = ys[idx], z = zs[idx];
      nx[bid * Sc + i2] = make_float4(x, y, z, fmaf(z, z, fmaf(y, y, x * x)));
      float* ob = out0 + (size_t)bid * 3 * Sc;
      ob[i2] = x; ob[Sc + i2] = y; ob[2 * Sc + i2] = z;
    }
  } else if (bid < 264) {
    int i = (bid - 8) * 256 + t;
    int b = i >> 13, n = i & 8191;
    const float* xb = xyz + (size_t)b * 3 * Nc;
    float x = xb[n], y = xb[Nc + n], z = xb[2 * Nc + n];
    xyzT[i] = make_float4(x, y, z, fmaf(z, z, fmaf(y, y, x * x)));
  } else {
    float* wl = (float*)smemc;  // 64*64 floats
    float* bl = wl + 64 * 64;
    for (int i2 = t; i2 < 64 * 64; i2 += 256) {
      int c = i2 >> 6, o = i2 & 63;
      wl[i2] = w00[o * 67 + 3 + c];
    }
    if (t < 64) bl[t] = b00[t];
    __syncthreads();
    pproj_body((bid - 264) * 256 + t, pts, wl, bl, P);
  }
}

// ---------------- wave-cooperative 32-NN (unchanged) ----------------
__global__ __launch_bounds__(256) void knn_kernel(const float4* __restrict__ xyzT,
                                                  const float4* __restrict__ newxyz,
                                                  int* __restrict__ knn) {
  int lane = threadIdx.x & 63;
  int sub = lane >> 5;
  int l32 = lane & 31;
  int waveId = blockIdx.x * 4 + (threadIdx.x >> 6);
  int q = waveId * 2 + sub;
  int b = q >> 10;
  float4 qv = newxyz[q];
  const float4* pb = xyzT + (size_t)b * Nc;
  unsigned long long lk = ~0ull;
  for (int t0 = 0; t0 < Nc; t0 += 32) {
    float4 p = pb[t0 + l32];
    float dot = fmaf(qv.z, p.z, fmaf(qv.y, p.y, qv.x * p.x));
    float d = fmaf(-2.f, dot, qv.w + p.w);
    unsigned fu = __float_as_uint(d);
    fu ^= (unsigned)(-(int)(fu >> 31)) | 0x80000000u;
    unsigned long long ck = ((unsigned long long)fu << 32) | (unsigned)(t0 + l32);
    unsigned long long worst = __shfl(lk, 31, 32);
    unsigned long long bal = __ballot(ck < worst);
    if (((unsigned)(bal >> (sub * 32))) == 0u) continue;
#pragma unroll
    for (int k = 2; k <= 32; k <<= 1) {
#pragma unroll
      for (int j = k >> 1; j > 0; j >>= 1) {
        unsigned long long o = __shfl_xor(ck, j, 32);
        bool up = ((l32 & k) == 0);
        bool lower = ((l32 & j) == 0);
        unsigned long long mn = (o < ck) ? o : ck;
        unsigned long long mx = (o < ck) ? ck : o;
        ck = (up == lower) ? mn : mx;
      }
    }
    unsigned long long rev = __shfl(ck, 31 - l32, 32);
    unsigned long long m0 = (rev < lk) ? rev : lk;
#pragma unroll
    for (int j = 16; j > 0; j >>= 1) {
      unsigned long long o = __shfl_xor(m0, j, 32);
      bool lower = ((l32 & j) == 0);
      unsigned long long mn = (o < m0) ? o : m0;
      unsigned long long mx = (o < m0) ? m0 : o;
      m0 = lower ? mn : mx;
    }
    lk = m0;
  }
  knn[(size_t)q * 32 + l32] = (int)(lk & 0xFFFFFFFFu);
}

// ---------------- layer1: gather + xyz part + fused stats; y position-major ----------------
template <int K>
__global__ __launch_bounds__(256) void conv1s_kernel(const float4* __restrict__ xyzT,
                                                     const float4* __restrict__ nx,
                                                     const int* __restrict__ knn,
                                                     const float* __restrict__ P,
                                                     const float* __restrict__ w0,
                                                     const float* __restrict__ b0,
                                                     float* __restrict__ y,
                                                     float* __restrict__ part, int Pos) {
  __shared__ alignas(16) float wx[64], wy[64], wz[64];
  __shared__ alignas(16) v2f wst[16][64];
  if (threadIdx.x < 64) {
    int o = threadIdx.x;
    wx[o] = w0[o * 67];
    wy[o] = w0[o * 67 + 1];
    wz[o] = w0[o * 67 + 2];
  }
  __syncthreads();
  int gp = blockIdx.x * 256 + threadIdx.x;
  int b = gp / Pos, r = gp % Pos;
  int s = r / K, kk = r & (K - 1);
  int n = knn[((size_t)(b * Sc + s)) * 32 + kk];
  float4 c4 = nx[b * Sc + s];
  float4 p4 = xyzT[(size_t)b * Nc + n];
  v2f dx2 = {p4.x - c4.x, p4.x - c4.x};
  v2f dy2 = {p4.y - c4.y, p4.y - c4.y};
  v2f dz2 = {p4.z - c4.z, p4.z - c4.z};
  const float4* Pn = (const float4*)(P + ((size_t)b * Nc + n) * 64);
  v2f acc[32];
#pragma unroll
  for (int o4 = 0; o4 < 16; o4++) {
    float4 v = Pn[o4];
    acc[2 * o4] = (v2f){v.x, v.y};
    acc[2 * o4 + 1] = (v2f){v.z, v.w};
  }
  const v2f* wx2 = (const v2f*)wx;
  const v2f* wy2 = (const v2f*)wy;
  const v2f* wz2 = (const v2f*)wz;
#pragma unroll
  for (int o2 = 0; o2 < 32; o2++) acc[o2] = __builtin_elementwise_fma(wx2[o2], dx2, acc[o2]);
#pragma unroll
  for (int o2 = 0; o2 < 32; o2++) acc[o2] = __builtin_elementwise_fma(wy2[o2], dy2, acc[o2]);
#pragma unroll
  for (int o2 = 0; o2 < 32; o2++) acc[o2] = __builtin_elementwise_fma(wz2[o2], dz2, acc[o2]);
  // position-major store: 16 contiguous float4 per position
  float4* yb = (float4*)(y + ((size_t)b * Pos + r) * 64);
#pragma unroll
  for (int o4 = 0; o4 < 16; o4++)
    yb[o4] = make_float4(acc[2 * o4].x, acc[2 * o4].y, acc[2 * o4 + 1].x, acc[2 * o4 + 1].y);
  int lane = threadIdx.x & 63, w = threadIdx.x >> 6;
  int row = w * 4 + (lane >> 4);
  bool lead = (lane & 15) == 15;
#pragma unroll
  for (int o2 = 0; o2 < 32; o2++) {
    float v0 = acc[o2].x, v1 = acc[o2].y;
    v2f s0 = dpp_rowsum2((v2f){v0, v0 * v0});
    v2f s1 = dpp_rowsum2((v2f){v1, v1 * v1});
    if (lead) { wst[row][2 * o2] = s0; wst[row][2 * o2 + 1] = s1; }
  }
  __syncthreads();
  if (threadIdx.x < 64) {
    int o = threadIdx.x;
    v2f sv = (v2f){0.f, 0.f};
#pragma unroll
    for (int rr = 0; rr < 16; rr++) sv += wst[rr][o];
    ((v2f*)part)[(size_t)blockIdx.x * 64 + o] = sv;
  }
}

// ---------------- bn finalize ----------------
__global__ __launch_bounds__(256) void bnfinA_kernel(const float* __restrict__ part,
                                                     const float* __restrict__ g,
                                                     const float* __restrict__ be,
                                                     float* __restrict__ bn, int C, int nblk,
                                                     float invcnt) {
  int c = blockIdx.x;
  v2f sq = (v2f){0.f, 0.f};
  for (int i = threadIdx.x; i < nblk; i += 256) sq += ((const v2f*)part)[(size_t)i * C + c];
  sq = dpp_rowsum2(sq);
  sq = dpp_sumstep2<0x142, 0xA>(sq);
  sq = dpp_sumstep2<0x143, 0xC>(sq);
  __shared__ v2f ls[4];
  int w = threadIdx.x >> 6;
  if ((threadIdx.x & 63) == 63) ls[w] = sq;
  __syncthreads();
  if (threadIdx.x == 0) {
    v2f tt = ls[0] + ls[1] + ls[2] + ls[3];
    float m = tt.x * invcnt;
    float v = tt.y * invcnt - m * m;
    float sc = g[c] / sqrtf(v + BN_EPS);
    bn[c * 2] = sc;
    bn[c * 2 + 1] = fmaf(-m, sc, be[c]);
  }
}

// ---------------- conv matmul body: pos-major in, chunked double-buffered prefetch ------
template <int CI, int CO>
__device__ __forceinline__ void conv_body(const float* __restrict__ xin,
                                          const float* __restrict__ wl,
                                          const float* __restrict__ bnl,
                                          const float* __restrict__ bl, v2f* acc) {
  constexpr int CO2 = CO / 2;
  const v2f* bl2 = (const v2f*)bl;
#pragma unroll
  for (int o2 = 0; o2 < CO2; o2++) acc[o2] = bl2[o2];
  const float4* xin4 = (const float4*)xin;
  float4 cur[4], nxt[4];
#pragma unroll
  for (int q = 0; q < 4; q++) cur[q] = xin4[q];
  for (int ch = 0; ch < CI; ch += 16) {
    if (ch + 16 < CI) {
#pragma unroll
      for (int q = 0; q < 4; q++) nxt[q] = xin4[(ch >> 2) + 4 + q];
    }
#pragma unroll
    for (int cc = 0; cc < 16; cc++) {
      float xv = ((const float*)cur)[cc];
      int c = ch + cc;
      xv = fmaxf(fmaf(xv, bnl[2 * c], bnl[2 * c + 1]), 0.f);
      v2f xv2 = {xv, xv};
      const float4* wr4 = (const float4*)(wl + c * CO);
#pragma unroll
      for (int o4 = 0; o4 < CO / 4; o4++) {
        float4 wv = wr4[o4];
        acc[2 * o4] = __builtin_elementwise_fma((v2f){wv.x, wv.y}, xv2, acc[2 * o4]);
        acc[2 * o4 + 1] = __builtin_elementwise_fma((v2f){wv.z, wv.w}, xv2, acc[2 * o4 + 1]);
      }
    }
#pragma unroll
    for (int q = 0; q < 4; q++) cur[q] = nxt[q];
  }
}

// ---------------- mid layer: pos-major in/out, fused stats (+pproj tail) ----------------
template <int CI, int CO, bool TAIL>
__global__ __launch_bounds__(256) void conv2s_kernel(const float* __restrict__ yin,
                                                     const float* __restrict__ w1,
                                                     const float* __restrict__ b1,
                                                     const float* __restrict__ bn,
                                                     float* __restrict__ yout,
                                                     float* __restrict__ part, int Pos, int nconv,
                                                     const float* __restrict__ pts,
                                                     const float* __restrict__ w10,
                                                     const float* __restrict__ b10,
                                                     float* __restrict__ P) {
  constexpr int CO2 = CO / 2;
  __shared__ alignas(16) float wl[CI * CO];
  __shared__ alignas(16) float bnl[2 * CI];
  __shared__ alignas(16) float bl[CO];
  __shared__ alignas(16) v2f wst[16][CO];
  if (TAIL && (int)blockIdx.x >= nconv) {
    for (int i2 = threadIdx.x; i2 < 64 * 64; i2 += 256) {
      int c = i2 >> 6, o = i2 & 63;
      wl[i2] = w10[o * 67 + 3 + c];
    }
    if (threadIdx.x < 64) bl[threadIdx.x] = b10[threadIdx.x];
    __syncthreads();
    pproj_body(((int)blockIdx.x - nconv) * 256 + threadIdx.x, pts, wl, bl, P);
    return;
  }
  for (int i2 = threadIdx.x; i2 < CI * CO; i2 += 256) {
    int c = i2 / CO, o = i2 % CO;
    wl[i2] = w1[o * CI + c];
  }
  for (int i2 = threadIdx.x; i2 < 2 * CI; i2 += 256) bnl[i2] = bn[i2];
  if (threadIdx.x < CO) bl[threadIdx.x] = b1[threadIdx.x];
  __syncthreads();
  int gp = blockIdx.x * 256 + threadIdx.x;
  int b = gp / Pos, r = gp % Pos;
  v2f acc[CO2];
  conv_body<CI, CO>(yin + ((size_t)b * Pos + r) * CI, wl, bnl, bl, acc);
  float4* yo = (float4*)(yout + ((size_t)b * Pos + r) * CO);
#pragma unroll
  for (int o4 = 0; o4 < CO / 4; o4++)
    yo[o4] = make_float4(acc[2 * o4].x, acc[2 * o4].y, acc[2 * o4 + 1].x, acc[2 * o4 + 1].y);
  int lane = threadIdx.x & 63, w = threadIdx.x >> 6;
  int row = w * 4 + (lane >> 4);
  bool lead = (lane & 15) == 15;
#pragma unroll
  for (int o2 = 0; o2 < CO2; o2++) {
    float v0 = acc[o2].x, v1 = acc[o2].y;
    v2f s0 = dpp_rowsum2((v2f){v0, v0 * v0});
    v2f s1 = dpp_rowsum2((v2f){v1, v1 * v1});
    if (lead) { wst[row][2 * o2] = s0; wst[row][2 * o2 + 1] = s1; }
  }
  __syncthreads();
  if (threadIdx.x < CO) {
    int o = threadIdx.x;
    v2f sv = (v2f){0.f, 0.f};
#pragma unroll
    for (int rr = 0; rr < 16; rr++) sv += wst[rr][o];
    ((v2f*)part)[(size_t)blockIdx.x * CO + o] = sv;
  }
}

// ---------------- last layer: pos-major in + DPP per-K max/min + fused stats --------------
template <int CI, int K>
__global__ __launch_bounds__(256) void conv3m_kernel(const float* __restrict__ yin,
                                                     const float* __restrict__ w2,
                                                     const float* __restrict__ b2,
                                                     const float* __restrict__ bn,
                                                     float* __restrict__ ymax,
                                                     float* __restrict__ ymin,
                                                     float* __restrict__ part, int Pos) {
  constexpr int CO = 128;
  constexpr int CO2 = CO / 2;
  __shared__ alignas(16) float wl[CI * CO];
  __shared__ alignas(16) float bnl[2 * CI];
  __shared__ alignas(16) float bl[CO];
  __shared__ alignas(16) v2f wst[16][CO];
  for (int i2 = threadIdx.x; i2 < CI * CO; i2 += 256) {
    int c = i2 / CO, o = i2 % CO;
    wl[i2] = w2[o * CI + c];
  }
  for (int i2 = threadIdx.x; i2 < 2 * CI; i2 += 256) bnl[i2] = bn[i2];
  if (threadIdx.x < CO) bl[threadIdx.x] = b2[threadIdx.x];
  __syncthreads();
  int gp = blockIdx.x * 256 + threadIdx.x;
  int b = gp / Pos, r = gp % Pos;
  int s = r / K;
  v2f acc[CO2];
  conv_body<CI, CO>(yin + ((size_t)b * Pos + r) * CI, wl, bnl, bl, acc);
  int lane = threadIdx.x & 63, w = threadIdx.x >> 6;
  int row = w * 4 + (lane >> 4);
  bool lead = (lane & 15) == 15;
  bool wrt = (lane & (K - 1)) == (K - 1);
#pragma unroll
  for (int o2 = 0; o2 < CO2; o2++) {
    float v0 = acc[o2].x, v1 = acc[o2].y;
    float mx0 = dpp_maxK<K>(v0), mn0 = dpp_minK<K>(v0);
    float mx1 = dpp_maxK<K>(v1), mn1 = dpp_minK<K>(v1);
    if (wrt) {
      ymax[((size_t)b * CO + 2 * o2) * Sc + s] = mx0;
      ymin[((size_t)b * CO + 2 * o2) * Sc + s] = mn0;
      ymax[((size_t)b * CO + 2 * o2 + 1) * Sc + s] = mx1;
      ymin[((size_t)b * CO + 2 * o2 + 1) * Sc + s] = mn1;
    }
    v2f s0 = dpp_rowsum2((v2f){v0, v0 * v0});
    v2f s1 = dpp_rowsum2((v2f){v1, v1 * v1});
    if (lead) { wst[row][2 * o2] = s0; wst[row][2 * o2 + 1] = s1; }
  }
  __syncthreads();
  if (threadIdx.x < CO) {
    int o = threadIdx.x;
    v2f sv = (v2f){0.f, 0.f};
#pragma unroll
    for (int rr = 0; rr < 16; rr++) sv += wst[rr][o];
    ((v2f*)part)[(size_t)blockIdx.x * CO + o] = sv;
  }
}

__global__ __launch_bounds__(256) void finout_kernel(const float* __restrict__ ymax,
                                                     const float* __restrict__ ymin,
                                                     const float* __restrict__ bn,
                                                     float* __restrict__ out1, int coff) {
  int i = blockIdx.x * 256 + threadIdx.x;  // B*128*S
  int b = i / (128 * Sc);
  int rest = i % (128 * Sc);
  int o = rest / Sc, s = rest % Sc;
  float sc = bn[o * 2], sh = bn[o * 2 + 1];
  float v = (sc >= 0.f) ? ymax[i] : ymin[i];  // ReLU∘affine is monotone; max over k
  out1[((size_t)b * 256 + coff + o) * Sc + s] = fmaxf(fmaf(v, sc, sh), 0.f);
}

extern "C" void kernel_launch(void* const* d_in, const int* in_sizes, int n_in,
                              void* d_out, int out_size, void* d_ws, size_t ws_size,
                              hipStream_t stream) {
  const float* xyz = (const float*)d_in[0];
  const float* pts = (const float*)d_in[1];
  float* ws = (float*)d_ws;
  float* out0 = (float*)d_out;
  float* out1 = out0 + Bc * 3 * Sc;

  float4* xyzT = (float4*)(ws + 0);
  float4* nx = (float4*)(ws + 262144);
  int* knn = (int*)(ws + 294912);
  float* P = ws + 557056;
  float* y0 = ws + 4751360;
  float* y1 = ws + 21528576;
  float* ymax = ws + 46694400;
  float* ymin = ws + 47742976;
  float* part = ws + 48791552;
  float* bn1 = ws + 49053696;
  float* bn2 = ws + 49053824;
  float* bn3 = ws + 49054016;

  mega_kernel<<<520, 256, 0, stream>>>(xyz, pts, (const float*)d_in[2], (const float*)d_in[3],
                                       xyzT, nx, out0, P);
  knn_kernel<<<(Bc * Sc) / 8, 256, 0, stream>>>(xyzT, nx, knn);

  for (int br = 0; br < 2; br++) {
    int base = 2 + br * 12;
    const float* w0 = (const float*)d_in[base + 0];
    const float* b0 = (const float*)d_in[base + 1];
    const float* g0 = (const float*)d_in[base + 2];
    const float* be0 = (const float*)d_in[base + 3];
    const float* w1 = (const float*)d_in[base + 4];
    const float* b1 = (const float*)d_in[base + 5];
    const float* g1 = (const float*)d_in[base + 6];
    const float* be1 = (const float*)d_in[base + 7];
    const float* w2 = (const float*)d_in[base + 8];
    const float* b2 = (const float*)d_in[base + 9];
    const float* g2 = (const float*)d_in[base + 10];
    const float* be2 = (const float*)d_in[base + 11];
    int K = br ? 32 : 16;
    int Pos = Sc * K;
    int CO2 = br ? 96 : 64;
    float invcnt = 1.f / (float)(Bc * Pos);
    int nblk = (Bc * Pos) / 256;

    if (br == 0)
      conv1s_kernel<16><<<nblk, 256, 0, stream>>>(xyzT, nx, knn, P, w0, b0, y0, part, Pos);
    else
      conv1s_kernel<32><<<nblk, 256, 0, stream>>>(xyzT, nx, knn, P, w0, b0, y0, part, Pos);
    bnfinA_kernel<<<64, 256, 0, stream>>>(part, g0, be0, bn1, 64, nblk, invcnt);

    if (br == 0)
      conv2s_kernel<64, 64, true><<<nblk + 256, 256, 0, stream>>>(
          y0, w1, b1, bn1, y1, part, Pos, nblk, pts, (const float*)d_in[14],
          (const float*)d_in[15], P);
    else
      conv2s_kernel<64, 96, false><<<nblk, 256, 0, stream>>>(y0, w1, b1, bn1, y1, part, Pos,
                                                             nblk, nullptr, nullptr, nullptr,
                                                             nullptr);
    bnfinA_kernel<<<CO2, 256, 0, stream>>>(part, g1, be1, bn2, CO2, nblk, invcnt);

    if (br == 0)
      conv3m_kernel<64, 16><<<nblk, 256, 0, stream>>>(y1, w2, b2, bn2, ymax, ymin, part, Pos);
    else
      conv3m_kernel<96, 32><<<nblk, 256, 0, stream>>>(y1, w2, b2, bn2, ymax, ymin, part, Pos);
    bnfinA_kernel<<<128, 256, 0, stream>>>(part, g2, be2, bn3, 128, nblk, invcnt);
    finout_kernel<<<(Bc * 128 * Sc) / 256, 256, 0, stream>>>(ymax, ymin, bn3, out1, br * 128);
  }
  (void)in_sizes; (void)n_in; (void)out_size; (void)ws_size;
}

// Round 8
// 1548.368 us; speedup vs baseline: 1.1864x; 1.1864x over previous
//
#include <hip/hip_runtime.h>
#include <math.h>

#define BN_EPS 1e-5f
constexpr int Bc = 8, Nc = 8192, Sc = 1024, CINc = 64;

typedef float v2f __attribute__((ext_vector_type(2)));

// ---------------- DPP helpers ----------------
template <int CTRL, int RMASK>
__device__ __forceinline__ unsigned long long dpp_maxu64(unsigned long long k) {
  int lo = (int)(unsigned)k, hi = (int)(unsigned)(k >> 32);
  int olo = __builtin_amdgcn_update_dpp(lo, lo, CTRL, RMASK, 0xF, false);
  int ohi = __builtin_amdgcn_update_dpp(hi, hi, CTRL, RMASK, 0xF, false);
  unsigned long long ok = ((unsigned long long)(unsigned)ohi << 32) | (unsigned)olo;
  return ok > k ? ok : k;
}
template <int CTRL, int RMASK>
__device__ __forceinline__ v2f dpp_sumstep2(v2f v) {
  int olo = __builtin_amdgcn_update_dpp(0, __float_as_int(v.x), CTRL, RMASK, 0xF, false);
  int ohi = __builtin_amdgcn_update_dpp(0, __float_as_int(v.y), CTRL, RMASK, 0xF, false);
  v2f o = {__int_as_float(olo), __int_as_float(ohi)};
  return v + o;
}
__device__ __forceinline__ v2f dpp_sum64v2(v2f v) {
  v = dpp_sumstep2<0x111, 0xF>(v);
  v = dpp_sumstep2<0x112, 0xF>(v);
  v = dpp_sumstep2<0x114, 0xF>(v);
  v = dpp_sumstep2<0x118, 0xF>(v);
  v = dpp_sumstep2<0x142, 0xA>(v);
  v = dpp_sumstep2<0x143, 0xC>(v);
  return v;  // lane63 holds total
}
template <int CTRL>
__device__ __forceinline__ v2f dpp_pkmax(v2f v) {
  int ox = __builtin_amdgcn_update_dpp(__float_as_int(v.x), __float_as_int(v.x), CTRL, 0xF, 0xF, false);
  int oy = __builtin_amdgcn_update_dpp(__float_as_int(v.y), __float_as_int(v.y), CTRL, 0xF, 0xF, false);
  v2f o = {__int_as_float(ox), __int_as_float(oy)};
  return __builtin_elementwise_max(v, o);
}
template <int CTRL>
__device__ __forceinline__ v2f dpp_pkmin(v2f v) {
  int ox = __builtin_amdgcn_update_dpp(__float_as_int(v.x), __float_as_int(v.x), CTRL, 0xF, 0xF, false);
  int oy = __builtin_amdgcn_update_dpp(__float_as_int(v.y), __float_as_int(v.y), CTRL, 0xF, 0xF, false);
  v2f o = {__int_as_float(ox), __int_as_float(oy)};
  return __builtin_elementwise_min(v, o);
}

// ---------------- shared pproj body (P[n][64] = W_pts . points + bias) ----------------
__device__ __forceinline__ void pproj_body(int i, const float* __restrict__ pts,
                                           const float* __restrict__ wl,
                                           const float* __restrict__ bl,
                                           float* __restrict__ P) {
  int b = i >> 13, n = i & 8191;
  const float* pb = pts + (size_t)b * CINc * Nc + n;
  v2f acc[32];
  const v2f* bl2 = (const v2f*)bl;
#pragma unroll
  for (int o2 = 0; o2 < 32; o2++) acc[o2] = bl2[o2];
  for (int c = 0; c < CINc; c++) {
    float xv = pb[(size_t)c * Nc];
    v2f xv2 = {xv, xv};
    const v2f* wr = (const v2f*)(wl + c * 64);
#pragma unroll
    for (int o2 = 0; o2 < 32; o2++) acc[o2] = __builtin_elementwise_fma(wr[o2], xv2, acc[o2]);
  }
  float4* Pn = (float4*)(P + (size_t)i * 64);
#pragma unroll
  for (int o4 = 0; o4 < 16; o4++)
    Pn[o4] = make_float4(acc[2 * o4].x, acc[2 * o4].y, acc[2 * o4 + 1].x, acc[2 * o4 + 1].y);
}

// ------- mega: blocks 0-7 fps (r4-proven 512t body), 8-135 xyzt, 136-263 pproj0, 264-391 pproj1
__global__ __launch_bounds__(512) void mega_kernel(const float* __restrict__ xyz,
                                                   const float* __restrict__ pts,
                                                   const float* __restrict__ w00,
                                                   const float* __restrict__ b00,
                                                   const float* __restrict__ w10,
                                                   const float* __restrict__ b10,
                                                   float4* __restrict__ xyzT,
                                                   float4* __restrict__ nx,
                                                   float* __restrict__ out0,
                                                   float* __restrict__ P0,
                                                   float* __restrict__ P1) {
  __shared__ alignas(16) char smemc[102528];
  int bid = blockIdx.x, t = threadIdx.x;
  if (bid < 8) {
    // ---- FPS (r4-proven): scalar dist + inline argmax, all-LDS, 1 barrier/iter ----
    float* xs = (float*)smemc;
    float* ys = xs + Nc;
    float* zs = ys + Nc;
    int* idxs = (int*)(smemc + 98304);
    unsigned long long* red = (unsigned long long*)(smemc + 102400);  // [2][8]
    const float* xb = xyz + (size_t)bid * 3 * Nc;
    float px[16], py[16], pz[16], dd[16];
#pragma unroll
    for (int j = 0; j < 16; j++) {
      int n = j * 512 + t;
      float x = xb[n], y = xb[Nc + n], z = xb[2 * Nc + n];
      px[j] = x; py[j] = y; pz[j] = z;
      xs[n] = x; ys[n] = y; zs[n] = z;
      dd[j] = 1e10f;
    }
    int w = t >> 6;
    __syncthreads();
    int curIdx = 0;
    for (int i = 0; i < Sc; i++) {
      float cx = xs[curIdx], cy = ys[curIdx], cz = zs[curIdx];  // LDS broadcast
      if (t == 0) idxs[i] = curIdx;
      float bd = -1.f;
      int bnidx = 0;
#pragma unroll
      for (int j = 0; j < 16; j++) {
        float dx = px[j] - cx, dy = py[j] - cy, dz = pz[j] - cz;
        float d = fmaf(dz, dz, fmaf(dy, dy, dx * dx));
        d = fminf(dd[j], d);
        dd[j] = d;
        if (d > bd) { bd = d; bnidx = j * 512 + t; }  // strict >: first index wins (jnp.argmax)
      }
      unsigned long long key =
          ((unsigned long long)__float_as_uint(bd) << 32) | (unsigned)(~bnidx);
      key = dpp_maxu64<0x111, 0xF>(key);  // row_shr:1
      key = dpp_maxu64<0x112, 0xF>(key);  // row_shr:2
      key = dpp_maxu64<0x114, 0xF>(key);  // row_shr:4
      key = dpp_maxu64<0x118, 0xF>(key);  // row_shr:8
      key = dpp_maxu64<0x142, 0xA>(key);  // row_bcast15
      key = dpp_maxu64<0x143, 0xC>(key);  // row_bcast31
      if ((t & 63) == 63) red[(i & 1) * 8 + w] = key;
      __syncthreads();
      const unsigned long long* rr = red + (i & 1) * 8;
      unsigned long long k2 = rr[0];
#pragma unroll
      for (int u = 1; u < 8; u++) {
        unsigned long long o = rr[u];
        k2 = (o > k2) ? o : k2;
      }
      curIdx = (int)(~(unsigned)(k2 & 0xFFFFFFFFull));
    }
    __syncthreads();
    for (int i2 = t; i2 < Sc; i2 += 512) {
      int idx = idxs[i2];
      float x = xs[idx], y = ys[idx], z = zs[idx];
      nx[bid * Sc + i2] = make_float4(x, y, z, fmaf(z, z, fmaf(y, y, x * x)));
      float* ob = out0 + (size_t)bid * 3 * Sc;
      ob[i2] = x; ob[Sc + i2] = y; ob[2 * Sc + i2] = z;
    }
  } else if (bid < 136) {
    int i = (bid - 8) * 512 + t;
    int b = i >> 13, n = i & 8191;
    const float* xb = xyz + (size_t)b * 3 * Nc;
    float x = xb[n], y = xb[Nc + n], z = xb[2 * Nc + n];
    xyzT[i] = make_float4(x, y, z, fmaf(z, z, fmaf(y, y, x * x)));
  } else {
    bool second = bid >= 264;
    const float* ww = second ? w10 : w00;
    const float* bb = second ? b10 : b00;
    float* PP = second ? P1 : P0;
    float* wl = (float*)smemc;  // 64*64 floats
    float* bl = wl + 64 * 64;
    for (int i2 = t; i2 < 64 * 64; i2 += 512) {
      int c = i2 >> 6, o = i2 & 63;
      wl[i2] = ww[o * 67 + 3 + c];
    }
    if (t < 64) bl[t] = bb[t];
    __syncthreads();
    pproj_body(((bid - (second ? 264 : 136)) * 512) + t, pts, wl, bl, PP);
  }
}

// ---------------- wave-cooperative 32-NN (unchanged) ----------------
__global__ __launch_bounds__(256) void knn_kernel(const float4* __restrict__ xyzT,
                                                  const float4* __restrict__ newxyz,
                                                  int* __restrict__ knn) {
  int lane = threadIdx.x & 63;
  int sub = lane >> 5;
  int l32 = lane & 31;
  int waveId = blockIdx.x * 4 + (threadIdx.x >> 6);
  int q = waveId * 2 + sub;
  int b = q >> 10;
  float4 qv = newxyz[q];
  const float4* pb = xyzT + (size_t)b * Nc;
  unsigned long long lk = ~0ull;
  for (int t0 = 0; t0 < Nc; t0 += 32) {
    float4 p = pb[t0 + l32];
    float dot = fmaf(qv.z, p.z, fmaf(qv.y, p.y, qv.x * p.x));
    float d = fmaf(-2.f, dot, qv.w + p.w);
    unsigned fu = __float_as_uint(d);
    fu ^= (unsigned)(-(int)(fu >> 31)) | 0x80000000u;
    unsigned long long ck = ((unsigned long long)fu << 32) | (unsigned)(t0 + l32);
    unsigned long long worst = __shfl(lk, 31, 32);
    unsigned long long bal = __ballot(ck < worst);
    if (((unsigned)(bal >> (sub * 32))) == 0u) continue;
#pragma unroll
    for (int k = 2; k <= 32; k <<= 1) {
#pragma unroll
      for (int j = k >> 1; j > 0; j >>= 1) {
        unsigned long long o = __shfl_xor(ck, j, 32);
        bool up = ((l32 & k) == 0);
        bool lower = ((l32 & j) == 0);
        unsigned long long mn = (o < ck) ? o : ck;
        unsigned long long mx = (o < ck) ? ck : o;
        ck = (up == lower) ? mn : mx;
      }
    }
    unsigned long long rev = __shfl(ck, 31 - l32, 32);
    unsigned long long m0 = (rev < lk) ? rev : lk;
#pragma unroll
    for (int j = 16; j > 0; j >>= 1) {
      unsigned long long o = __shfl_xor(m0, j, 32);
      bool lower = ((l32 & j) == 0);
      unsigned long long mn = (o < m0) ? o : m0;
      unsigned long long mx = (o < m0) ? m0 : o;
      m0 = lower ? mn : mx;
    }
    lk = m0;
  }
  knn[(size_t)q * 32 + l32] = (int)(lk & 0xFFFFFFFFu);
}

// ---------------- layer1: gather + xyz part + fused stats; y position-major ----------------
template <int K>
__global__ __launch_bounds__(256) void conv1s_kernel(const float4* __restrict__ xyzT,
                                                     const float4* __restrict__ nx,
                                                     const int* __restrict__ knn,
                                                     const float* __restrict__ P,
                                                     const float* __restrict__ w0,
                                                     const float* __restrict__ b0,
                                                     float* __restrict__ y,
                                                     float* __restrict__ part, int Pos) {
  __shared__ alignas(16) float wx[64], wy[64], wz[64];
  __shared__ alignas(16) v2f wst[16][64];
  if (threadIdx.x < 64) {
    int o = threadIdx.x;
    wx[o] = w0[o * 67];
    wy[o] = w0[o * 67 + 1];
    wz[o] = w0[o * 67 + 2];
  }
  __syncthreads();
  int gp = blockIdx.x * 256 + threadIdx.x;
  int b = gp / Pos, r = gp % Pos;
  int s = r / K, kk = r & (K - 1);
  int n = knn[((size_t)(b * Sc + s)) * 32 + kk];
  float4 c4 = nx[b * Sc + s];
  float4 p4 = xyzT[(size_t)b * Nc + n];
  v2f dx2 = {p4.x - c4.x, p4.x - c4.x};
  v2f dy2 = {p4.y - c4.y, p4.y - c4.y};
  v2f dz2 = {p4.z - c4.z, p4.z - c4.z};
  const float4* Pn = (const float4*)(P + ((size_t)b * Nc + n) * 64);
  v2f acc[32];
#pragma unroll
  for (int o4 = 0; o4 < 16; o4++) {
    float4 v = Pn[o4];
    acc[2 * o4] = (v2f){v.x, v.y};
    acc[2 * o4 + 1] = (v2f){v.z, v.w};
  }
  const v2f* wx2 = (const v2f*)wx;
  const v2f* wy2 = (const v2f*)wy;
  const v2f* wz2 = (const v2f*)wz;
#pragma unroll
  for (int o2 = 0; o2 < 32; o2++) acc[o2] = __builtin_elementwise_fma(wx2[o2], dx2, acc[o2]);
#pragma unroll
  for (int o2 = 0; o2 < 32; o2++) acc[o2] = __builtin_elementwise_fma(wy2[o2], dy2, acc[o2]);
#pragma unroll
  for (int o2 = 0; o2 < 32; o2++) acc[o2] = __builtin_elementwise_fma(wz2[o2], dz2, acc[o2]);
  float4* yb = (float4*)(y + ((size_t)b * Pos + r) * 64);
#pragma unroll
  for (int o4 = 0; o4 < 16; o4++)
    yb[o4] = make_float4(acc[2 * o4].x, acc[2 * o4].y, acc[2 * o4 + 1].x, acc[2 * o4 + 1].y);
  int lane = threadIdx.x & 63, w = threadIdx.x >> 6;
  int row = w * 4 + (lane >> 4);
  bool lead = (lane & 15) == 15;
#pragma unroll
  for (int o2 = 0; o2 < 32; o2++) {
    float v0 = acc[o2].x, v1 = acc[o2].y;
    v2f s0 = (v2f){v0, v0 * v0};
    s0 = dpp_sumstep2<0x111, 0xF>(s0);
    s0 = dpp_sumstep2<0x112, 0xF>(s0);
    s0 = dpp_sumstep2<0x114, 0xF>(s0);
    s0 = dpp_sumstep2<0x118, 0xF>(s0);
    v2f s1 = (v2f){v1, v1 * v1};
    s1 = dpp_sumstep2<0x111, 0xF>(s1);
    s1 = dpp_sumstep2<0x112, 0xF>(s1);
    s1 = dpp_sumstep2<0x114, 0xF>(s1);
    s1 = dpp_sumstep2<0x118, 0xF>(s1);
    if (lead) { wst[row][2 * o2] = s0; wst[row][2 * o2 + 1] = s1; }
  }
  __syncthreads();
  if (threadIdx.x < 64) {
    int o = threadIdx.x;
    v2f sv = (v2f){0.f, 0.f};
#pragma unroll
    for (int rr = 0; rr < 16; rr++) sv += wst[rr][o];
    ((v2f*)part)[(size_t)blockIdx.x * 64 + o] = sv;
  }
}

// ---------------- bn finalize ----------------
__global__ __launch_bounds__(256) void bnfinA_kernel(const float* __restrict__ part,
                                                     const float* __restrict__ g,
                                                     const float* __restrict__ be,
                                                     float* __restrict__ bn, int C, int nblk,
                                                     float invcnt) {
  int c = blockIdx.x;
  v2f sq = (v2f){0.f, 0.f};
  for (int i = threadIdx.x; i < nblk; i += 256) sq += ((const v2f*)part)[(size_t)i * C + c];
  sq = dpp_sum64v2(sq);
  __shared__ v2f ls[4];
  int w = threadIdx.x >> 6;
  if ((threadIdx.x & 63) == 63) ls[w] = sq;
  __syncthreads();
  if (threadIdx.x == 0) {
    v2f tt = ls[0] + ls[1] + ls[2] + ls[3];
    float m = tt.x * invcnt;
    float v = tt.y * invcnt - m * m;
    float sc = g[c] / sqrtf(v + BN_EPS);
    bn[c * 2] = sc;
    bn[c * 2 + 1] = fmaf(-m, sc, be[c]);
  }
}

// ------- convB: 4 positions/thread x CO/4 channels/wave; weights reused 4x per b128 -------
// K==0: conv2 mode (store yout); K>0: conv3 mode (per-K max/min to ymax/ymin).
template <int CI, int CO, int K>
__global__ __launch_bounds__(256) void convB_kernel(const float* __restrict__ yin,
                                                    const float* __restrict__ wt,
                                                    const float* __restrict__ bb,
                                                    const float* __restrict__ bn,
                                                    float* __restrict__ yout,
                                                    float* __restrict__ ymax,
                                                    float* __restrict__ ymin,
                                                    float* __restrict__ part, int Pos) {
  constexpr int COq = CO / 4;   // channels per wave
  constexpr int COq2 = COq / 2; // v2f per wave
  __shared__ alignas(16) float wl[CI * CO];
  __shared__ float bnl[2 * CI];
  __shared__ float bl[CO];
  for (int i = threadIdx.x; i < CI * CO; i += 256) {
    int c = i / CO, o = i % CO;
    wl[i] = wt[o * CI + c];
  }
  for (int i = threadIdx.x; i < 2 * CI; i += 256) bnl[i] = bn[i];
  if (threadIdx.x < CO) bl[threadIdx.x] = bb[threadIdx.x];
  __syncthreads();
  int w = threadIdx.x >> 6, l = threadIdx.x & 63;
  int cb = w * COq;
  int bpb = Pos / 256;
  int b = blockIdx.x / bpb;
  int r0 = (blockIdx.x % bpb) * 256 + l * 4;
  const float* xin = yin + ((size_t)b * Pos + r0) * CI;
  v2f acc[4][COq2];
#pragma unroll
  for (int p = 0; p < 4; p++)
#pragma unroll
    for (int q = 0; q < COq2; q++) acc[p][q] = ((const v2f*)(bl + cb))[q];
  float4 cur[4], nxt[4];
#pragma unroll
  for (int p = 0; p < 4; p++) cur[p] = ((const float4*)(xin + p * CI))[0];
  for (int ch = 0; ch < CI; ch += 4) {
    if (ch + 4 < CI) {
#pragma unroll
      for (int p = 0; p < 4; p++) nxt[p] = ((const float4*)(xin + p * CI))[(ch >> 2) + 1];
    }
#pragma unroll
    for (int cc = 0; cc < 4; cc++) {
      int c = ch + cc;
      float scv = bnl[2 * c], shv = bnl[2 * c + 1];
      float xv0 = fmaxf(fmaf(((const float*)&cur[0])[cc], scv, shv), 0.f);
      float xv1 = fmaxf(fmaf(((const float*)&cur[1])[cc], scv, shv), 0.f);
      float xv2 = fmaxf(fmaf(((const float*)&cur[2])[cc], scv, shv), 0.f);
      float xv3 = fmaxf(fmaf(((const float*)&cur[3])[cc], scv, shv), 0.f);
      v2f x0 = {xv0, xv0}, x1 = {xv1, xv1}, x2 = {xv2, xv2}, x3 = {xv3, xv3};
      const float4* wr = (const float4*)(wl + c * CO + cb);
#pragma unroll
      for (int o4 = 0; o4 < COq / 4; o4++) {
        float4 wv = wr[o4];
        v2f w01 = {wv.x, wv.y}, w23 = {wv.z, wv.w};
        acc[0][2 * o4] = __builtin_elementwise_fma(w01, x0, acc[0][2 * o4]);
        acc[0][2 * o4 + 1] = __builtin_elementwise_fma(w23, x0, acc[0][2 * o4 + 1]);
        acc[1][2 * o4] = __builtin_elementwise_fma(w01, x1, acc[1][2 * o4]);
        acc[1][2 * o4 + 1] = __builtin_elementwise_fma(w23, x1, acc[1][2 * o4 + 1]);
        acc[2][2 * o4] = __builtin_elementwise_fma(w01, x2, acc[2][2 * o4]);
        acc[2][2 * o4 + 1] = __builtin_elementwise_fma(w23, x2, acc[2][2 * o4 + 1]);
        acc[3][2 * o4] = __builtin_elementwise_fma(w01, x3, acc[3][2 * o4]);
        acc[3][2 * o4 + 1] = __builtin_elementwise_fma(w23, x3, acc[3][2 * o4 + 1]);
      }
    }
#pragma unroll
    for (int p = 0; p < 4; p++) cur[p] = nxt[p];
  }
  if (K == 0) {
#pragma unroll
    for (int p = 0; p < 4; p++) {
      float4* yo = (float4*)(yout + ((size_t)b * Pos + r0 + p) * CO + cb);
#pragma unroll
      for (int o4 = 0; o4 < COq / 4; o4++)
        yo[o4] = make_float4(acc[p][2 * o4].x, acc[p][2 * o4].y, acc[p][2 * o4 + 1].x,
                             acc[p][2 * o4 + 1].y);
    }
  } else {
    int s = r0 / K;
    bool wrt = (K == 16) ? ((l & 3) == 3) : ((l & 7) == 7);
#pragma unroll
    for (int q = 0; q < COq2; q++) {
      v2f mx = __builtin_elementwise_max(__builtin_elementwise_max(acc[0][q], acc[1][q]),
                                         __builtin_elementwise_max(acc[2][q], acc[3][q]));
      v2f mn = __builtin_elementwise_min(__builtin_elementwise_min(acc[0][q], acc[1][q]),
                                         __builtin_elementwise_min(acc[2][q], acc[3][q]));
      mx = dpp_pkmax<0x111>(mx);
      mx = dpp_pkmax<0x112>(mx);
      if (K == 32) mx = dpp_pkmax<0x114>(mx);
      mn = dpp_pkmin<0x111>(mn);
      mn = dpp_pkmin<0x112>(mn);
      if (K == 32) mn = dpp_pkmin<0x114>(mn);
      if (wrt) {
        ymax[((size_t)b * CO + cb + 2 * q) * Sc + s] = mx.x;
        ymax[((size_t)b * CO + cb + 2 * q + 1) * Sc + s] = mx.y;
        ymin[((size_t)b * CO + cb + 2 * q) * Sc + s] = mn.x;
        ymin[((size_t)b * CO + cb + 2 * q + 1) * Sc + s] = mn.y;
      }
    }
  }
  // fused stats: per channel (sum, sumsq) over this block's 256 positions
#pragma unroll
  for (int q = 0; q < COq2; q++) {
    v2f sv = acc[0][q] + acc[1][q] + acc[2][q] + acc[3][q];
    v2f sq = acc[0][q] * acc[0][q];
    sq = __builtin_elementwise_fma(acc[1][q], acc[1][q], sq);
    sq = __builtin_elementwise_fma(acc[2][q], acc[2][q], sq);
    sq = __builtin_elementwise_fma(acc[3][q], acc[3][q], sq);
    sv = dpp_sum64v2(sv);
    sq = dpp_sum64v2(sq);
    if (l == 63) {
      ((v2f*)part)[(size_t)blockIdx.x * CO + cb + 2 * q] = (v2f){sv.x, sq.x};
      ((v2f*)part)[(size_t)blockIdx.x * CO + cb + 2 * q + 1] = (v2f){sv.y, sq.y};
    }
  }
}

__global__ __launch_bounds__(256) void finout_kernel(const float* __restrict__ ymax,
                                                     const float* __restrict__ ymin,
                                                     const float* __restrict__ bn,
                                                     float* __restrict__ out1, int coff) {
  int i = blockIdx.x * 256 + threadIdx.x;  // B*128*S
  int b = i / (128 * Sc);
  int rest = i % (128 * Sc);
  int o = rest / Sc, s = rest % Sc;
  float sc = bn[o * 2], sh = bn[o * 2 + 1];
  float v = (sc >= 0.f) ? ymax[i] : ymin[i];  // ReLU∘affine is monotone; max over k
  out1[((size_t)b * 256 + coff + o) * Sc + s] = fmaxf(fmaf(v, sc, sh), 0.f);
}

extern "C" void kernel_launch(void* const* d_in, const int* in_sizes, int n_in,
                              void* d_out, int out_size, void* d_ws, size_t ws_size,
                              hipStream_t stream) {
  const float* xyz = (const float*)d_in[0];
  const float* pts = (const float*)d_in[1];
  float* ws = (float*)d_ws;
  float* out0 = (float*)d_out;
  float* out1 = out0 + Bc * 3 * Sc;

  float4* xyzT = (float4*)(ws + 0);
  float4* nx = (float4*)(ws + 262144);
  int* knn = (int*)(ws + 294912);
  float* P0 = ws + 557056;
  float* y0 = ws + 4751360;                 // br0: 8.39M, br1: 16.78M (ends 21528576)
  float* y1 = ws + 21528576;                // br0: 8.39M, br1: 25.17M (ends 46694400)
  float* P1 = ws + 29917184;                // aliases y1[8.39M..12.58M): clobbered only by conv2-br1
  float* ymax = ws + 46694400;
  float* ymin = ws + 47742976;
  float* part = ws + 48791552;
  float* bn1 = ws + 49053696;
  float* bn2 = ws + 49053824;
  float* bn3 = ws + 49054016;

  mega_kernel<<<392, 512, 0, stream>>>(xyz, pts, (const float*)d_in[2], (const float*)d_in[3],
                                       (const float*)d_in[14], (const float*)d_in[15], xyzT, nx,
                                       out0, P0, P1);
  knn_kernel<<<(Bc * Sc) / 8, 256, 0, stream>>>(xyzT, nx, knn);

  for (int br = 0; br < 2; br++) {
    int base = 2 + br * 12;
    const float* w0 = (const float*)d_in[base + 0];
    const float* b0 = (const float*)d_in[base + 1];
    const float* g0 = (const float*)d_in[base + 2];
    const float* be0 = (const float*)d_in[base + 3];
    const float* w1 = (const float*)d_in[base + 4];
    const float* b1 = (const float*)d_in[base + 5];
    const float* g1 = (const float*)d_in[base + 6];
    const float* be1 = (const float*)d_in[base + 7];
    const float* w2 = (const float*)d_in[base + 8];
    const float* b2 = (const float*)d_in[base + 9];
    const float* g2 = (const float*)d_in[base + 10];
    const float* be2 = (const float*)d_in[base + 11];
    int K = br ? 32 : 16;
    int Pos = Sc * K;
    int CO2 = br ? 96 : 64;
    float invcnt = 1.f / (float)(Bc * Pos);
    int nblk = (Bc * Pos) / 256;
    const float* P = br ? P1 : P0;

    if (br == 0)
      conv1s_kernel<16><<<nblk, 256, 0, stream>>>(xyzT, nx, knn, P, w0, b0, y0, part, Pos);
    else
      conv1s_kernel<32><<<nblk, 256, 0, stream>>>(xyzT, nx, knn, P, w0, b0, y0, part, Pos);
    bnfinA_kernel<<<64, 256, 0, stream>>>(part, g0, be0, bn1, 64, nblk, invcnt);

    if (br == 0)
      convB_kernel<64, 64, 0><<<nblk, 256, 0, stream>>>(y0, w1, b1, bn1, y1, nullptr, nullptr,
                                                        part, Pos);
    else
      convB_kernel<64, 96, 0><<<nblk, 256, 0, stream>>>(y0, w1, b1, bn1, y1, nullptr, nullptr,
                                                        part, Pos);
    bnfinA_kernel<<<CO2, 256, 0, stream>>>(part, g1, be1, bn2, CO2, nblk, invcnt);

    if (br == 0)
      convB_kernel<64, 128, 16><<<nblk, 256, 0, stream>>>(y1, w2, b2, bn2, nullptr, ymax, ymin,
                                                          part, Pos);
    else
      convB_kernel<96, 128, 32><<<nblk, 256, 0, stream>>>(y1, w2, b2, bn2, nullptr, ymax, ymin,
                                                          part, Pos);
    bnfinA_kernel<<<128, 256, 0, stream>>>(part, g2, be2, bn3, 128, nblk, invcnt);
    finout_kernel<<<(Bc * 128 * Sc) / 256, 256, 0, stream>>>(ymax, ymin, bn3, out1, br * 128);
  }
  (void)in_sizes; (void)n_in; (void)out_size; (void)ws_size;
}